// Round 17
// baseline (241.535 us; speedup 1.0000x reference)
//
#include <hip/hip_runtime.h>
#include <math.h>

// out[M,N] = round-clip(x*(127/max(x))) int8  @  weight_q[N,K]^T int8
//            -> i32 acc -> * (max(x)/127) * qscales[n] + bias[n]
#define MDIM 8192
#define KDIM 4096
#define NDIM 4096

typedef int v4i __attribute__((ext_vector_type(4)));

__device__ __forceinline__ void gload_lds16(const void* g, void* l) {
  __builtin_amdgcn_global_load_lds(
      (const __attribute__((address_space(1))) void*)g,
      (__attribute__((address_space(3))) void*)l,
      16, 0, 0);
}

__device__ __forceinline__ float key_to_float(unsigned key) {
  unsigned b = (key & 0x80000000u) ? (key & 0x7FFFFFFFu) : ~key;
  return __uint_as_float(b);
}

// ------- kernel 1: FUSED weight-repack (blocks 0..PACK_B-1) + max(x) ----------
constexpr int PACK_B = 768, MAX_B = 1280;

__global__ void __launch_bounds__(256) kprep(const int* __restrict__ w,
                                             signed char* __restrict__ w8,
                                             const float* __restrict__ x,
                                             unsigned int* __restrict__ key_out) {
  if (blockIdx.x < PACK_B) {
    __shared__ int smode;
    int ok = 1;
    #pragma unroll
    for (int i = 0; i < 16; ++i) {
      int v = w[threadIdx.x * 16 + i];
      ok &= (v >= -128) & (v <= 127);
    }
    if (threadIdx.x == 0) smode = 1;
    __syncthreads();
    if (!ok) atomicAnd(&smode, 0);
    __syncthreads();
    const int mode = smode;

    const int n16 = NDIM * KDIM / 16;
    int tid = blockIdx.x * blockDim.x + threadIdx.x;
    int stride = PACK_B * blockDim.x;
    int4* dst = (int4*)w8;
    if (mode) {
      const int4* src = (const int4*)w;
      for (int i = tid; i < n16; i += stride) {
        int4 r;
        #pragma unroll
        for (int q = 0; q < 4; ++q) {
          int4 a = src[(size_t)i * 4 + q];
          int packed = (a.x & 255) | ((a.y & 255) << 8) |
                       ((a.z & 255) << 16) | ((a.w & 255) << 24);
          ((int*)&r)[q] = packed;
        }
        dst[i] = r;
      }
    } else {
      const int4* src = (const int4*)w;
      for (int i = tid; i < n16; i += stride) dst[i] = src[i];
    }
  } else {
    const int n4 = MDIM * KDIM / 4;
    int b = blockIdx.x - PACK_B;
    int tid = b * blockDim.x + threadIdx.x;
    int stride = MAX_B * blockDim.x;
    float m = -3.4e38f;
    const float4* x4 = (const float4*)x;
    for (int i = tid; i < n4; i += stride) {
      float4 v = x4[i];
      m = fmaxf(m, fmaxf(fmaxf(v.x, v.y), fmaxf(v.z, v.w)));
    }
    #pragma unroll
    for (int off = 32; off > 0; off >>= 1)
      m = fmaxf(m, __shfl_down(m, off, 64));
    __shared__ float sm[4];
    int lane = threadIdx.x & 63, wv = threadIdx.x >> 6;
    if (lane == 0) sm[wv] = m;
    __syncthreads();
    if (threadIdx.x == 0) {
      m = fmaxf(fmaxf(sm[0], sm[1]), fmaxf(sm[2], sm[3]));
      unsigned bb = __float_as_uint(m);
      unsigned key = (bb & 0x80000000u) ? ~bb : (bb | 0x80000000u);
      atomicMax(key_out, key);
    }
  }
}

// ---------------- kernel 2: quantize x -> int8 ----------------
__device__ __forceinline__ int pack4(float4 v, float s) {
  int q0 = (int)fminf(fmaxf(rintf(v.x * s), -128.f), 127.f);
  int q1 = (int)fminf(fmaxf(rintf(v.y * s), -128.f), 127.f);
  int q2 = (int)fminf(fmaxf(rintf(v.z * s), -128.f), 127.f);
  int q3 = (int)fminf(fmaxf(rintf(v.w * s), -128.f), 127.f);
  return (q0 & 255) | ((q1 & 255) << 8) | ((q2 & 255) << 16) | ((q3 & 255) << 24);
}

__global__ void __launch_bounds__(256) kquant(const float* __restrict__ x,
                                              signed char* __restrict__ x8,
                                              const unsigned* __restrict__ keyp) {
  float s = 127.0f / key_to_float(*keyp);
  const int n16 = MDIM * KDIM / 16;
  int tid = blockIdx.x * blockDim.x + threadIdx.x;
  int stride = gridDim.x * blockDim.x;
  const float4* x4 = (const float4*)x;
  int4* out16 = (int4*)x8;
  for (int i = tid; i < n16; i += stride) {
    const float4* src = x4 + (size_t)i * 4;
    int4 r;
    r.x = pack4(src[0], s);
    r.y = pack4(src[1], s);
    r.z = pack4(src[2], s);
    r.w = pack4(src[3], s);
    out16[i] = r;
  }
}

// ---- kernel 3: int8 256x256 GEMM, 16 waves (4 waves/SIMD), unpinned body ------
// BM=BN=256, BK=128, 1024 threads = 16 waves in a 4x4 grid; wave tile 64x64 =
// 4x4 frags 16x16 -> acc 64 regs (fits the 128-reg/4-wave-per-SIMD cap).
// Same LDS image as R16 (128 KiB, 1 block/CU), same 32 K-tiles, same unpinned
// schedule: { stage t+1 into [par^1] | sched_barrier | reads consumption-first
// + 32 MFMA unpinned | vmcnt(0) + barrier }. KEY CHANGE: 4 waves/SIMD (was 2)
// -> intra-SIMD TLP overlaps one wave's lgkmcnt waits with others' MFMAs.
// Per wave per tile: 16 ds_read_b128 + 32 MFMA; per thread: 4 gload_lds.
constexpr int BM = 256, BN = 256, BK = 128;
constexpr int NT = KDIM / BK;  // 32

__device__ __forceinline__ v4i mfma_i8(v4i a, v4i b, v4i c) {
  return __builtin_amdgcn_mfma_i32_16x16x64_i8(a, b, c, 0, 0, 0);
}

__global__ void __launch_bounds__(1024, 4) kgemm(
    const signed char* __restrict__ A8,   // [M][K]
    const signed char* __restrict__ W8,   // [N][K]
    const float* __restrict__ qs,
    const float* __restrict__ bias,
    const unsigned* __restrict__ keyp,
    float* __restrict__ out) {            // [M][N]
  __shared__ alignas(1024) signed char lds[2][2][256 * 128];  // [par][A/B] 128 KiB

  const int nbn = NDIM / BN;                  // 16
  const int nwg = (MDIM / BM) * nbn;          // 512 (divisible by 8)
  int bid = blockIdx.x;
  int wg = (bid & 7) * (nwg / 8) + (bid >> 3);  // XCD-contiguous
  const int brow = (wg / nbn) * BM;
  const int bcol = (wg % nbn) * BN;

  const int tid = threadIdx.x;
  const int lane = tid & 63;
  const int wv = tid >> 6;                    // 0..15
  const int wr = wv >> 2, wc = wv & 3;        // 4 x 4 wave grid
  const int lhi = lane >> 4, llo = lane & 15;

  const signed char* Abase = A8 + (size_t)brow * KDIM;
  const signed char* Bbase = W8 + (size_t)bcol * KDIM;

  // Stage one 256x128 operand tile: 2048 16B-chunks, 1024 thr x 2.
  // Chunk p: row r = p>>3, slot s = p&7; global k-chunk g = s ^ (r&7)
  // (XOR involution, undone on read -- rule #21). Linear LDS dest.
  auto stageA = [&](int t) {
    signed char* dst = &lds[t & 1][0][0];
    const size_t k0 = (size_t)t * BK;
    #pragma unroll
    for (int l = 0; l < 2; ++l) {
      int p = l * 1024 + tid;
      int r = p >> 3, s = p & 7;
      int g = s ^ (r & 7);
      gload_lds16(Abase + (size_t)r * KDIM + k0 + g * 16, dst + p * 16);
    }
  };
  auto stageB = [&](int t) {
    signed char* dst = &lds[t & 1][1][0];
    const size_t k0 = (size_t)t * BK;
    #pragma unroll
    for (int l = 0; l < 2; ++l) {
      int p = l * 1024 + tid;
      int r = p >> 3, s = p & 7;
      int g = s ^ (r & 7);
      gload_lds16(Bbase + (size_t)r * KDIM + k0 + g * 16, dst + p * 16);
    }
  };
  // Fragment reads (undo the XOR with row & 7 == llo & 7).
  auto readA = [&](int par, int mi, int ks) -> v4i {
    int r = wr * 64 + mi * 16 + llo;
    int s = (ks * 4 + lhi) ^ (llo & 7);
    return *(const v4i*)&lds[par][0][r * 128 + s * 16];
  };
  auto readB = [&](int par, int ni, int ks) -> v4i {
    int r = wc * 64 + ni * 16 + llo;
    int s = (ks * 4 + lhi) ^ (llo & 7);
    return *(const v4i*)&lds[par][1][r * 128 + s * 16];
  };

  v4i acc[4][4];
  v4i zero = {0, 0, 0, 0};
  #pragma unroll
  for (int i = 0; i < 4; ++i)
    #pragma unroll
    for (int j = 0; j < 4; ++j) acc[i][j] = zero;

  // Prologue: stage tile 0, drain, barrier.
  stageA(0); stageB(0);
  asm volatile("s_waitcnt vmcnt(0)" ::: "memory");
  __builtin_amdgcn_s_barrier();

  #pragma unroll 2
  for (int t = 0; t < NT; ++t) {
    const int par = t & 1;
    v4i afr[4][2], bfr[4][2];

    // Stage ALL of tile t+1 into [par^1] first (max flight time); one
    // sched_barrier keeps the stage issues above the compute.
    if (t + 1 < NT) { stageA(t + 1); stageB(t + 1); }
    __builtin_amdgcn_sched_barrier(0);

    // Reads consumption-first; MFMAs unpinned (compiler software-pipelines
    // with counted lgkmcnt; 4 waves/SIMD cover residual waits).
    #pragma unroll
    for (int ni = 0; ni < 4; ++ni) {
      bfr[ni][0] = readB(par, ni, 0);
      bfr[ni][1] = readB(par, ni, 1);
    }
    #pragma unroll
    for (int mi = 0; mi < 4; ++mi) {
      afr[mi][0] = readA(par, mi, 0);
      afr[mi][1] = readA(par, mi, 1);
    }

    #pragma unroll
    for (int mi = 0; mi < 4; ++mi)
      #pragma unroll
      for (int ni = 0; ni < 4; ++ni) {
        acc[mi][ni] = mfma_i8(afr[mi][0], bfr[ni][0], acc[mi][ni]);
        acc[mi][ni] = mfma_i8(afr[mi][1], bfr[ni][1], acc[mi][ni]);
      }

    // Tile boundary: t+1 landed (issued a full tile ago) + all waves done
    // reading [par] before anyone stages into it next tile.
    asm volatile("s_waitcnt vmcnt(0)" ::: "memory");
    __builtin_amdgcn_s_barrier();
  }

  // epilogue: out = acc * (clampv/127) * qs[n] + bias[n]
  const float alpha = key_to_float(*keyp) * (1.0f / 127.0f);
  #pragma unroll
  for (int ni = 0; ni < 4; ++ni) {
    int n = bcol + wc * 64 + ni * 16 + llo;
    float sc = qs[n] * alpha;
    float bv = bias[n];
    #pragma unroll
    for (int mi = 0; mi < 4; ++mi) {
      int m0 = brow + wr * 64 + mi * 16 + lhi * 4;
      #pragma unroll
      for (int j = 0; j < 4; ++j)
        out[(size_t)(m0 + j) * NDIM + n] = (float)acc[mi][ni][j] * sc + bv;
    }
  }
}

extern "C" void kernel_launch(void* const* d_in, const int* in_sizes, int n_in,
                              void* d_out, int out_size, void* d_ws, size_t ws_size,
                              hipStream_t stream) {
  const float* x = (const float*)d_in[0];
  const int* wq = (const int*)d_in[1];       // integer input: int32 words
  const float* qscales = (const float*)d_in[2];
  const float* bias = (const float*)d_in[3];
  float* out = (float*)d_out;

  unsigned* keyp = (unsigned*)d_ws;
  signed char* x8 = (signed char*)d_ws + 256;
  signed char* w8 = x8 + (size_t)MDIM * KDIM;

  (void)hipMemsetAsync(keyp, 0, 4, stream);  // capture-safe
  kprep<<<PACK_B + MAX_B, 256, 0, stream>>>(wq, w8, x, keyp);
  kquant<<<2048, 256, 0, stream>>>(x, x8, keyp);
  kgemm<<<(MDIM / BM) * (NDIM / BN), 1024, 0, stream>>>(x8, w8, qscales, bias, keyp, out);
}

// Round 18
// 204.437 us; speedup vs baseline: 1.1815x; 1.1815x over previous
//
#include <hip/hip_runtime.h>
#include <math.h>

// out[M,N] = round-clip(x*(127/max(x))) int8  @  weight_q[N,K]^T int8
//            -> i32 acc -> * (max(x)/127) * qscales[n] + bias[n]
#define MDIM 8192
#define KDIM 4096
#define NDIM 4096

typedef int v4i __attribute__((ext_vector_type(4)));

__device__ __forceinline__ void gload_lds16(const void* g, void* l) {
  __builtin_amdgcn_global_load_lds(
      (const __attribute__((address_space(1))) void*)g,
      (__attribute__((address_space(3))) void*)l,
      16, 0, 0);
}

__device__ __forceinline__ float key_to_float(unsigned key) {
  unsigned b = (key & 0x80000000u) ? (key & 0x7FFFFFFFu) : ~key;
  return __uint_as_float(b);
}

// ------- kernel 1: FUSED weight-repack (blocks 0..PACK_B-1) + max(x) ----------
constexpr int PACK_B = 768, MAX_B = 1280;

__global__ void __launch_bounds__(256) kprep(const int* __restrict__ w,
                                             signed char* __restrict__ w8,
                                             const float* __restrict__ x,
                                             unsigned int* __restrict__ key_out) {
  if (blockIdx.x < PACK_B) {
    __shared__ int smode;
    int ok = 1;
    #pragma unroll
    for (int i = 0; i < 16; ++i) {
      int v = w[threadIdx.x * 16 + i];
      ok &= (v >= -128) & (v <= 127);
    }
    if (threadIdx.x == 0) smode = 1;
    __syncthreads();
    if (!ok) atomicAnd(&smode, 0);
    __syncthreads();
    const int mode = smode;

    const int n16 = NDIM * KDIM / 16;
    int tid = blockIdx.x * blockDim.x + threadIdx.x;
    int stride = PACK_B * blockDim.x;
    int4* dst = (int4*)w8;
    if (mode) {
      const int4* src = (const int4*)w;
      for (int i = tid; i < n16; i += stride) {
        int4 r;
        #pragma unroll
        for (int q = 0; q < 4; ++q) {
          int4 a = src[(size_t)i * 4 + q];
          int packed = (a.x & 255) | ((a.y & 255) << 8) |
                       ((a.z & 255) << 16) | ((a.w & 255) << 24);
          ((int*)&r)[q] = packed;
        }
        dst[i] = r;
      }
    } else {
      const int4* src = (const int4*)w;
      for (int i = tid; i < n16; i += stride) dst[i] = src[i];
    }
  } else {
    const int n4 = MDIM * KDIM / 4;
    int b = blockIdx.x - PACK_B;
    int tid = b * blockDim.x + threadIdx.x;
    int stride = MAX_B * blockDim.x;
    float m = -3.4e38f;
    const float4* x4 = (const float4*)x;
    for (int i = tid; i < n4; i += stride) {
      float4 v = x4[i];
      m = fmaxf(m, fmaxf(fmaxf(v.x, v.y), fmaxf(v.z, v.w)));
    }
    #pragma unroll
    for (int off = 32; off > 0; off >>= 1)
      m = fmaxf(m, __shfl_down(m, off, 64));
    __shared__ float sm[4];
    int lane = threadIdx.x & 63, wv = threadIdx.x >> 6;
    if (lane == 0) sm[wv] = m;
    __syncthreads();
    if (threadIdx.x == 0) {
      m = fmaxf(fmaxf(sm[0], sm[1]), fmaxf(sm[2], sm[3]));
      unsigned bb = __float_as_uint(m);
      unsigned key = (bb & 0x80000000u) ? ~bb : (bb | 0x80000000u);
      atomicMax(key_out, key);
    }
  }
}

// ---------------- kernel 2: quantize x -> int8 ----------------
__device__ __forceinline__ int pack4(float4 v, float s) {
  int q0 = (int)fminf(fmaxf(rintf(v.x * s), -128.f), 127.f);
  int q1 = (int)fminf(fmaxf(rintf(v.y * s), -128.f), 127.f);
  int q2 = (int)fminf(fmaxf(rintf(v.z * s), -128.f), 127.f);
  int q3 = (int)fminf(fmaxf(rintf(v.w * s), -128.f), 127.f);
  return (q0 & 255) | ((q1 & 255) << 8) | ((q2 & 255) << 16) | ((q3 & 255) << 24);
}

__global__ void __launch_bounds__(256) kquant(const float* __restrict__ x,
                                              signed char* __restrict__ x8,
                                              const unsigned* __restrict__ keyp) {
  float s = 127.0f / key_to_float(*keyp);
  const int n16 = MDIM * KDIM / 16;
  int tid = blockIdx.x * blockDim.x + threadIdx.x;
  int stride = gridDim.x * blockDim.x;
  const float4* x4 = (const float4*)x;
  int4* out16 = (int4*)x8;
  for (int i = tid; i < n16; i += stride) {
    const float4* src = x4 + (size_t)i * 4;
    int4 r;
    r.x = pack4(src[0], s);
    r.y = pack4(src[1], s);
    r.z = pack4(src[2], s);
    r.w = pack4(src[3], s);
    out16[i] = r;
  }
}

// ---- kernel 3: int8 256x256 GEMM, lead-1 stage, FULLY unpinned tile body ------
// R16 structure minus the last scheduling pin: no sched_barrier anywhere in the
// tile body; reads first in source order (earliest lgkmcnt chains), stage
// issues after (latency-tolerant; compiler hoists them as it sees fit).
// Dataflow (proven race-free): per tile { reads from [par] + stage t+1 into
// [par^1] + 64 MFMA, all compiler-scheduled | vmcnt(0) + barrier }.
constexpr int BM = 256, BN = 256, BK = 128;
constexpr int NT = KDIM / BK;  // 32

__device__ __forceinline__ v4i mfma_i8(v4i a, v4i b, v4i c) {
  return __builtin_amdgcn_mfma_i32_16x16x64_i8(a, b, c, 0, 0, 0);
}

__global__ void __launch_bounds__(512, 2) kgemm(
    const signed char* __restrict__ A8,   // [M][K]
    const signed char* __restrict__ W8,   // [N][K]
    const float* __restrict__ qs,
    const float* __restrict__ bias,
    const unsigned* __restrict__ keyp,
    float* __restrict__ out) {            // [M][N]
  __shared__ alignas(1024) signed char lds[2][2][2][128 * 128];  // [par][A/B][half]

  const int nbn = NDIM / BN;                  // 16
  const int nwg = (MDIM / BM) * nbn;          // 512 (divisible by 8)
  int bid = blockIdx.x;
  int wg = (bid & 7) * (nwg / 8) + (bid >> 3);  // XCD-contiguous
  const int brow = (wg / nbn) * BM;
  const int bcol = (wg % nbn) * BN;

  const int tid = threadIdx.x;
  const int lane = tid & 63;
  const int wv = tid >> 6;                    // 0..7
  const int wr = wv >> 2, wc = wv & 3;        // 2 x 4 wave grid
  const int lhi = lane >> 4, llo = lane & 15;

  const signed char* Abase = A8 + (size_t)brow * KDIM;
  const signed char* Bbase = W8 + (size_t)bcol * KDIM;

  // Stage A-half h / B-half h of K-tile t (linear LDS dest; XOR-pre-swizzled
  // global source, involution undone on read -- rule #21).
  auto stageA = [&](int t, int h) {
    signed char* dst = &lds[t & 1][0][h][0];
    const size_t k0 = (size_t)t * BK;
    #pragma unroll
    for (int l = 0; l < 2; ++l) {
      int p = l * 512 + tid;
      int r = p >> 3, s = p & 7;
      int R = ((r >> 6) << 7) + h * 64 + (r & 63);
      int g = s ^ (r & 7);
      gload_lds16(Abase + (size_t)R * KDIM + k0 + g * 16, dst + p * 16);
    }
  };
  auto stageB = [&](int t, int h) {
    signed char* dst = &lds[t & 1][1][h][0];
    const size_t k0 = (size_t)t * BK;
    #pragma unroll
    for (int l = 0; l < 2; ++l) {
      int p = l * 512 + tid;
      int r = p >> 3, s = p & 7;
      int R = ((r >> 5) << 6) + h * 32 + (r & 31);
      int g = s ^ (r & 7);
      gload_lds16(Bbase + (size_t)R * KDIM + k0 + g * 16, dst + p * 16);
    }
  };
  auto readA = [&](int par, int mi, int ks) -> v4i {
    int h = mi >> 2;
    int r = wr * 64 + (mi & 3) * 16 + llo;
    int s = (ks * 4 + lhi) ^ (llo & 7);
    return *(const v4i*)&lds[par][0][h][r * 128 + s * 16];
  };
  auto readB = [&](int par, int ni, int ks) -> v4i {
    int h = ni >> 1;
    int r = wc * 32 + (ni & 1) * 16 + llo;
    int s = (ks * 4 + lhi) ^ (llo & 7);
    return *(const v4i*)&lds[par][1][h][r * 128 + s * 16];
  };

  v4i acc[8][4];
  v4i zero = {0, 0, 0, 0};
  #pragma unroll
  for (int i = 0; i < 8; ++i)
    #pragma unroll
    for (int j = 0; j < 4; ++j) acc[i][j] = zero;

  // Prologue: stage tile 0, drain, barrier.
  stageA(0, 0); stageA(0, 1); stageB(0, 0); stageB(0, 1);
  asm volatile("s_waitcnt vmcnt(0)" ::: "memory");
  __builtin_amdgcn_s_barrier();

  #pragma unroll 2
  for (int t = 0; t < NT; ++t) {
    const int par = t & 1;
    v4i afr[8][2], bfr[4][2];

    // Reads first (earliest lgkmcnt chains), consumption-first order.
    #pragma unroll
    for (int ni = 0; ni < 2; ++ni) {
      bfr[ni][0] = readB(par, ni, 0);
      bfr[ni][1] = readB(par, ni, 1);
    }
    #pragma unroll
    for (int mi = 0; mi < 4; ++mi) {
      afr[mi][0] = readA(par, mi, 0);
      afr[mi][1] = readA(par, mi, 1);
    }
    #pragma unroll
    for (int ni = 2; ni < 4; ++ni) {
      bfr[ni][0] = readB(par, ni, 0);
      bfr[ni][1] = readB(par, ni, 1);
    }
    #pragma unroll
    for (int mi = 4; mi < 8; ++mi) {
      afr[mi][0] = readA(par, mi, 0);
      afr[mi][1] = readA(par, mi, 1);
    }

    // Stage ALL of tile t+1 into [par^1]; no pins -- compiler schedules the
    // issues among the reads/MFMAs (loads are independent of this tile).
    if (t + 1 < NT) {
      stageA(t + 1, 0); stageA(t + 1, 1);
      stageB(t + 1, 0); stageB(t + 1, 1);
    }

    #pragma unroll
    for (int mi = 0; mi < 8; ++mi)
      #pragma unroll
      for (int ni = 0; ni < 4; ++ni) {
        acc[mi][ni] = mfma_i8(afr[mi][0], bfr[ni][0], acc[mi][ni]);
        acc[mi][ni] = mfma_i8(afr[mi][1], bfr[ni][1], acc[mi][ni]);
      }

    // Tile boundary: t+1 landed (issued a full tile ago) + all waves done
    // reading [par] before anyone stages into it next tile.
    asm volatile("s_waitcnt vmcnt(0)" ::: "memory");
    __builtin_amdgcn_s_barrier();
  }

  // epilogue: out = acc * (clampv/127) * qs[n] + bias[n]
  const float alpha = key_to_float(*keyp) * (1.0f / 127.0f);
  #pragma unroll
  for (int ni = 0; ni < 4; ++ni) {
    int n = bcol + wc * 64 + ni * 16 + llo;
    float sc = qs[n] * alpha;
    float bv = bias[n];
    #pragma unroll
    for (int mi = 0; mi < 8; ++mi) {
      int m0 = brow + wr * 128 + mi * 16 + lhi * 4;
      #pragma unroll
      for (int j = 0; j < 4; ++j)
        out[(size_t)(m0 + j) * NDIM + n] = (float)acc[mi][ni][j] * sc + bv;
    }
  }
}

extern "C" void kernel_launch(void* const* d_in, const int* in_sizes, int n_in,
                              void* d_out, int out_size, void* d_ws, size_t ws_size,
                              hipStream_t stream) {
  const float* x = (const float*)d_in[0];
  const int* wq = (const int*)d_in[1];       // integer input: int32 words
  const float* qscales = (const float*)d_in[2];
  const float* bias = (const float*)d_in[3];
  float* out = (float*)d_out;

  unsigned* keyp = (unsigned*)d_ws;
  signed char* x8 = (signed char*)d_ws + 256;
  signed char* w8 = x8 + (size_t)MDIM * KDIM;

  (void)hipMemsetAsync(keyp, 0, 4, stream);  // capture-safe
  kprep<<<PACK_B + MAX_B, 256, 0, stream>>>(wq, w8, x, keyp);
  kquant<<<2048, 256, 0, stream>>>(x, x8, keyp);
  kgemm<<<(MDIM / BM) * (NDIM / BN), 512, 0, stream>>>(x8, w8, qscales, bias, keyp, out);
}

// Round 19
// 202.024 us; speedup vs baseline: 1.1956x; 1.0119x over previous
//
#include <hip/hip_runtime.h>
#include <math.h>

// out[M,N] = round-clip(x*(127/max(x))) int8  @  weight_q[N,K]^T int8
//            -> i32 acc -> * (max(x)/127) * qscales[n] + bias[n]
#define MDIM 8192
#define KDIM 4096
#define NDIM 4096

typedef int v4i __attribute__((ext_vector_type(4)));

__device__ __forceinline__ void gload_lds16(const void* g, void* l) {
  __builtin_amdgcn_global_load_lds(
      (const __attribute__((address_space(1))) void*)g,
      (__attribute__((address_space(3))) void*)l,
      16, 0, 0);
}

__device__ __forceinline__ float key_to_float(unsigned key) {
  unsigned b = (key & 0x80000000u) ? (key & 0x7FFFFFFFu) : ~key;
  return __uint_as_float(b);
}

// ------- kernel 1: FUSED weight-repack (blocks 0..PACK_B-1) + max(x) ----------
constexpr int PACK_B = 768, MAX_B = 1280;

__global__ void __launch_bounds__(256) kprep(const int* __restrict__ w,
                                             signed char* __restrict__ w8,
                                             const float* __restrict__ x,
                                             unsigned int* __restrict__ key_out) {
  if (blockIdx.x < PACK_B) {
    __shared__ int smode;
    int ok = 1;
    #pragma unroll
    for (int i = 0; i < 16; ++i) {
      int v = w[threadIdx.x * 16 + i];
      ok &= (v >= -128) & (v <= 127);
    }
    if (threadIdx.x == 0) smode = 1;
    __syncthreads();
    if (!ok) atomicAnd(&smode, 0);
    __syncthreads();
    const int mode = smode;

    const int n16 = NDIM * KDIM / 16;
    int tid = blockIdx.x * blockDim.x + threadIdx.x;
    int stride = PACK_B * blockDim.x;
    int4* dst = (int4*)w8;
    if (mode) {
      const int4* src = (const int4*)w;
      for (int i = tid; i < n16; i += stride) {
        int4 r;
        #pragma unroll
        for (int q = 0; q < 4; ++q) {
          int4 a = src[(size_t)i * 4 + q];
          int packed = (a.x & 255) | ((a.y & 255) << 8) |
                       ((a.z & 255) << 16) | ((a.w & 255) << 24);
          ((int*)&r)[q] = packed;
        }
        dst[i] = r;
      }
    } else {
      const int4* src = (const int4*)w;
      for (int i = tid; i < n16; i += stride) dst[i] = src[i];
    }
  } else {
    const int n4 = MDIM * KDIM / 4;
    int b = blockIdx.x - PACK_B;
    int tid = b * blockDim.x + threadIdx.x;
    int stride = MAX_B * blockDim.x;
    float m = -3.4e38f;
    const float4* x4 = (const float4*)x;
    for (int i = tid; i < n4; i += stride) {
      float4 v = x4[i];
      m = fmaxf(m, fmaxf(fmaxf(v.x, v.y), fmaxf(v.z, v.w)));
    }
    #pragma unroll
    for (int off = 32; off > 0; off >>= 1)
      m = fmaxf(m, __shfl_down(m, off, 64));
    __shared__ float sm[4];
    int lane = threadIdx.x & 63, wv = threadIdx.x >> 6;
    if (lane == 0) sm[wv] = m;
    __syncthreads();
    if (threadIdx.x == 0) {
      m = fmaxf(fmaxf(sm[0], sm[1]), fmaxf(sm[2], sm[3]));
      unsigned bb = __float_as_uint(m);
      unsigned key = (bb & 0x80000000u) ? ~bb : (bb | 0x80000000u);
      atomicMax(key_out, key);
    }
  }
}

// ---------------- kernel 2: quantize x -> int8 ----------------
__device__ __forceinline__ int pack4(float4 v, float s) {
  int q0 = (int)fminf(fmaxf(rintf(v.x * s), -128.f), 127.f);
  int q1 = (int)fminf(fmaxf(rintf(v.y * s), -128.f), 127.f);
  int q2 = (int)fminf(fmaxf(rintf(v.z * s), -128.f), 127.f);
  int q3 = (int)fminf(fmaxf(rintf(v.w * s), -128.f), 127.f);
  return (q0 & 255) | ((q1 & 255) << 8) | ((q2 & 255) << 16) | ((q3 & 255) << 24);
}

__global__ void __launch_bounds__(256) kquant(const float* __restrict__ x,
                                              signed char* __restrict__ x8,
                                              const unsigned* __restrict__ keyp) {
  float s = 127.0f / key_to_float(*keyp);
  const int n16 = MDIM * KDIM / 16;
  int tid = blockIdx.x * blockDim.x + threadIdx.x;
  int stride = gridDim.x * blockDim.x;
  const float4* x4 = (const float4*)x;
  int4* out16 = (int4*)x8;
  for (int i = tid; i < n16; i += stride) {
    const float4* src = x4 + (size_t)i * 4;
    int4 r;
    r.x = pack4(src[0], s);
    r.y = pack4(src[1], s);
    r.z = pack4(src[2], s);
    r.w = pack4(src[3], s);
    out16[i] = r;
  }
}

// ---- kernel 3: int8 256x256 GEMM, lead-1 stage, UNPINNED tile body ------------
// BEST MEASURED (R16: kgemm 128.1 us). Per tile: { stage ALL of t+1 into
// [par^1] | one sched_barrier (keeps stage issues ahead of the read chains;
// removing it cost +7 us, R18) | reads consumption-first + 64 MFMA unpinned
// (compiler software-pipelines with counted lgkmcnt) | vmcnt(0) + barrier }.
// WAR-safe: stages only touch [par^1], last read before this tile's opening
// barrier. RAW-safe: vmcnt(0)+barrier at tile end, stage-to-wait = full tile.
constexpr int BM = 256, BN = 256, BK = 128;
constexpr int NT = KDIM / BK;  // 32

__device__ __forceinline__ v4i mfma_i8(v4i a, v4i b, v4i c) {
  return __builtin_amdgcn_mfma_i32_16x16x64_i8(a, b, c, 0, 0, 0);
}

__global__ void __launch_bounds__(512, 2) kgemm(
    const signed char* __restrict__ A8,   // [M][K]
    const signed char* __restrict__ W8,   // [N][K]
    const float* __restrict__ qs,
    const float* __restrict__ bias,
    const unsigned* __restrict__ keyp,
    float* __restrict__ out) {            // [M][N]
  __shared__ alignas(1024) signed char lds[2][2][2][128 * 128];  // [par][A/B][half]

  const int nbn = NDIM / BN;                  // 16
  const int nwg = (MDIM / BM) * nbn;          // 512 (divisible by 8)
  int bid = blockIdx.x;
  int wg = (bid & 7) * (nwg / 8) + (bid >> 3);  // XCD-contiguous
  const int brow = (wg / nbn) * BM;
  const int bcol = (wg % nbn) * BN;

  const int tid = threadIdx.x;
  const int lane = tid & 63;
  const int wv = tid >> 6;                    // 0..7
  const int wr = wv >> 2, wc = wv & 3;        // 2 x 4 wave grid
  const int lhi = lane >> 4, llo = lane & 15;

  const signed char* Abase = A8 + (size_t)brow * KDIM;
  const signed char* Bbase = W8 + (size_t)bcol * KDIM;

  // Stage A-half h / B-half h of K-tile t (linear LDS dest; XOR-pre-swizzled
  // global source, involution undone on read -- rule #21).
  auto stageA = [&](int t, int h) {
    signed char* dst = &lds[t & 1][0][h][0];
    const size_t k0 = (size_t)t * BK;
    #pragma unroll
    for (int l = 0; l < 2; ++l) {
      int p = l * 512 + tid;
      int r = p >> 3, s = p & 7;
      int R = ((r >> 6) << 7) + h * 64 + (r & 63);
      int g = s ^ (r & 7);
      gload_lds16(Abase + (size_t)R * KDIM + k0 + g * 16, dst + p * 16);
    }
  };
  auto stageB = [&](int t, int h) {
    signed char* dst = &lds[t & 1][1][h][0];
    const size_t k0 = (size_t)t * BK;
    #pragma unroll
    for (int l = 0; l < 2; ++l) {
      int p = l * 512 + tid;
      int r = p >> 3, s = p & 7;
      int R = ((r >> 5) << 6) + h * 32 + (r & 31);
      int g = s ^ (r & 7);
      gload_lds16(Bbase + (size_t)R * KDIM + k0 + g * 16, dst + p * 16);
    }
  };
  auto readA = [&](int par, int mi, int ks) -> v4i {
    int h = mi >> 2;
    int r = wr * 64 + (mi & 3) * 16 + llo;
    int s = (ks * 4 + lhi) ^ (llo & 7);
    return *(const v4i*)&lds[par][0][h][r * 128 + s * 16];
  };
  auto readB = [&](int par, int ni, int ks) -> v4i {
    int h = ni >> 1;
    int r = wc * 32 + (ni & 1) * 16 + llo;
    int s = (ks * 4 + lhi) ^ (llo & 7);
    return *(const v4i*)&lds[par][1][h][r * 128 + s * 16];
  };

  v4i acc[8][4];
  v4i zero = {0, 0, 0, 0};
  #pragma unroll
  for (int i = 0; i < 8; ++i)
    #pragma unroll
    for (int j = 0; j < 4; ++j) acc[i][j] = zero;

  // Prologue: stage tile 0, drain, barrier.
  stageA(0, 0); stageA(0, 1); stageB(0, 0); stageB(0, 1);
  asm volatile("s_waitcnt vmcnt(0)" ::: "memory");
  __builtin_amdgcn_s_barrier();

  #pragma unroll 2
  for (int t = 0; t < NT; ++t) {
    const int par = t & 1;
    v4i afr[8][2], bfr[4][2];

    // Stage ALL of tile t+1 into [par^1] first (max flight time), then one
    // sched_barrier so the stage issues can't sink below the compute.
    if (t + 1 < NT) {
      stageA(t + 1, 0); stageA(t + 1, 1);
      stageB(t + 1, 0); stageB(t + 1, 1);
    }
    __builtin_amdgcn_sched_barrier(0);

    // Reads in consumption-first order; MFMAs unpinned after them. The
    // compiler interleaves with fine-grained lgkmcnt (software pipeline).
    #pragma unroll
    for (int ni = 0; ni < 2; ++ni) {
      bfr[ni][0] = readB(par, ni, 0);
      bfr[ni][1] = readB(par, ni, 1);
    }
    #pragma unroll
    for (int mi = 0; mi < 4; ++mi) {
      afr[mi][0] = readA(par, mi, 0);
      afr[mi][1] = readA(par, mi, 1);
    }
    #pragma unroll
    for (int ni = 2; ni < 4; ++ni) {
      bfr[ni][0] = readB(par, ni, 0);
      bfr[ni][1] = readB(par, ni, 1);
    }
    #pragma unroll
    for (int mi = 4; mi < 8; ++mi) {
      afr[mi][0] = readA(par, mi, 0);
      afr[mi][1] = readA(par, mi, 1);
    }

    #pragma unroll
    for (int mi = 0; mi < 8; ++mi)
      #pragma unroll
      for (int ni = 0; ni < 4; ++ni) {
        acc[mi][ni] = mfma_i8(afr[mi][0], bfr[ni][0], acc[mi][ni]);
        acc[mi][ni] = mfma_i8(afr[mi][1], bfr[ni][1], acc[mi][ni]);
      }

    // Tile boundary: t+1 landed (issued a full tile ago) + all waves done
    // reading [par] before anyone stages into it next tile.
    asm volatile("s_waitcnt vmcnt(0)" ::: "memory");
    __builtin_amdgcn_s_barrier();
  }

  // epilogue: out = acc * (clampv/127) * qs[n] + bias[n]
  const float alpha = key_to_float(*keyp) * (1.0f / 127.0f);
  #pragma unroll
  for (int ni = 0; ni < 4; ++ni) {
    int n = bcol + wc * 64 + ni * 16 + llo;
    float sc = qs[n] * alpha;
    float bv = bias[n];
    #pragma unroll
    for (int mi = 0; mi < 8; ++mi) {
      int m0 = brow + wr * 128 + mi * 16 + lhi * 4;
      #pragma unroll
      for (int j = 0; j < 4; ++j)
        out[(size_t)(m0 + j) * NDIM + n] = (float)acc[mi][ni][j] * sc + bv;
    }
  }
}

extern "C" void kernel_launch(void* const* d_in, const int* in_sizes, int n_in,
                              void* d_out, int out_size, void* d_ws, size_t ws_size,
                              hipStream_t stream) {
  const float* x = (const float*)d_in[0];
  const int* wq = (const int*)d_in[1];       // integer input: int32 words
  const float* qscales = (const float*)d_in[2];
  const float* bias = (const float*)d_in[3];
  float* out = (float*)d_out;

  unsigned* keyp = (unsigned*)d_ws;
  signed char* x8 = (signed char*)d_ws + 256;
  signed char* w8 = x8 + (size_t)MDIM * KDIM;

  (void)hipMemsetAsync(keyp, 0, 4, stream);  // capture-safe
  kprep<<<PACK_B + MAX_B, 256, 0, stream>>>(wq, w8, x, keyp);
  kquant<<<2048, 256, 0, stream>>>(x, x8, keyp);
  kgemm<<<(MDIM / BM) * (NDIM / BN), 512, 0, stream>>>(x8, w8, qscales, bias, keyp, out);
}